// Round 6
// baseline (562.795 us; speedup 1.0000x reference)
//
#include <hip/hip_runtime.h>
#include <math.h>

#define NT 17
#define NB 17       // one block per type
#define KCAP 300
#define KP 320      // padded column count for bf16 K' rows (640 B/row in global)
#define LROW 656    // LDS row stride bytes (16B-aligned, 656/4%32=4 breaks bank alias)
#define LCAP 208    // K' rows resident in LDS per block (spill -> global Ms2)
#define CH 2        // tiles (of 4 rows) per register chunk
#define NITER 30
// -1/tau * log2(e): M matrix is in base-2 log domain
#define MSCALE2 28.853900817779268f

typedef unsigned long long u64;
typedef float vfloat4 __attribute__((ext_vector_type(4)));
typedef float f32x2 __attribute__((ext_vector_type(2)));

#define EX2(x) __builtin_amdgcn_exp2f(x)
#define LG2(x) __builtin_amdgcn_logf(x)
#if __has_builtin(__builtin_amdgcn_rcpf)
#define RCP(x) __builtin_amdgcn_rcpf(x)
#else
#define RCP(x) (1.0f / (x))
#endif

// bf16 round-to-nearest-even pack helpers
__device__ inline unsigned bf16rne(float x) {
  unsigned u = __float_as_uint(x);
  return (u + 0x7FFFu + ((u >> 16) & 1u)) >> 16;
}
__device__ inline unsigned bfp(float lo, float hi) {
  return bf16rne(lo) | (bf16rne(hi) << 16);
}
#define BFLO(p) __uint_as_float((p) << 16)
#define BFHI(p) __uint_as_float((p) & 0xFFFF0000u)

// unpack a dword of 2 bf16 into an f32x2 (for v_pk_fma_f32 feeding)
__device__ inline f32x2 bf2up(unsigned u) {
  f32x2 r;
  r.x = BFLO(u);
  r.y = BFHI(u);
  return r;
}

// ---- meta layout ----
// [0..16]   typeCount
// [32..48]  typeOff

__device__ inline float selu_f(float x) {
  const float scale = 1.0507009873554804934193349852946f;
  const float alpha = 1.6732632423543772848170429916717f;
  return x > 0.f ? scale * x : scale * alpha * (EX2(x * 1.4426950408889634f) - 1.f);
}

// fused histogram + prefix + scatter (single block)
__global__ __launch_bounds__(1024) void k_bucket(const int* __restrict__ jt, int n,
    int* __restrict__ meta, int* __restrict__ perm, int* __restrict__ tys) {
  __shared__ int hist[NT];
  __shared__ int off[NT];
  __shared__ int cnt[NT];
  int tid = threadIdx.x;
  if (tid < NT) { hist[tid] = 0; cnt[tid] = 0; }
  __syncthreads();
  for (int i = tid; i < n; i += 1024) atomicAdd(&hist[jt[i]], 1);
  __syncthreads();
  if (tid == 0) {
    int o = 0;
    for (int t = 0; t < NT; t++) {
      off[t] = o; meta[32 + t] = o; meta[t] = hist[t]; o += hist[t];
    }
  }
  __syncthreads();
  for (int i = tid; i < n; i += 1024) {
    int t = jt[i];
    int pos = off[t] + atomicAdd(&cnt[t], 1);
    perm[pos] = i;
    tys[pos] = t;
  }
}

// h = selu(emb @ W1 + b1)   (n x D) @ (D x H)
__global__ __launch_bounds__(256) void k_hgemm(const float* __restrict__ A,
    const float* __restrict__ B, const float* __restrict__ bias,
    float* __restrict__ C, int n, int D, int H) {
  __shared__ __align__(16) float As[16][68];
  __shared__ __align__(16) float Bs[16][68];
  int tid = threadIdx.x;
  int i0 = blockIdx.x * 64, j0 = blockIdx.y * 64;
  int tx = tid & 15, ty = tid >> 4;
  int aI = tid & 63, aK = (tid >> 6) << 2;
  int bJ = (tid & 15) << 2, bK = tid >> 4;
  float acc[4][4] = {};
  for (int k0 = 0; k0 < D; k0 += 16) {
    float4 av = *(const float4*)(A + (size_t)(i0 + aI) * D + k0 + aK);
    float4 bv = *(const float4*)(B + (size_t)(k0 + bK) * H + j0 + bJ);
    __syncthreads();
    As[aK + 0][aI] = av.x; As[aK + 1][aI] = av.y; As[aK + 2][aI] = av.z; As[aK + 3][aI] = av.w;
    *(float4*)(&Bs[bK][bJ]) = bv;
    __syncthreads();
#pragma unroll
    for (int kk = 0; kk < 16; kk++) {
      float4 a4 = *(float4*)(&As[kk][ty << 2]);
      float4 b4 = *(float4*)(&Bs[kk][tx << 2]);
      float aa[4] = {a4.x, a4.y, a4.z, a4.w};
      float bb[4] = {b4.x, b4.y, b4.z, b4.w};
#pragma unroll
      for (int p = 0; p < 4; p++)
#pragma unroll
        for (int q = 0; q < 4; q++)
          acc[p][q] = fmaf(aa[p], bb[q], acc[p][q]);
    }
  }
#pragma unroll
  for (int p = 0; p < 4; p++) {
    int i = i0 + (ty << 2) + p;
    float o[4];
#pragma unroll
    for (int q = 0; q < 4; q++) {
      int j = j0 + (tx << 2) + q;
      o[q] = selu_f(acc[p][q] + bias[j]);
    }
    *(float4*)(C + (size_t)i * H + j0 + (tx << 2)) = make_float4(o[0], o[1], o[2], o[3]);
  }
}

// Ms[r][j] = -max(0, |h_r|^2+|p_j|^2-2*dot)/tau*log2e, rows type-sorted.
__global__ __launch_bounds__(256) void k_msort(const float* __restrict__ h,
    const float* __restrict__ P, const int* __restrict__ perm,
    float* __restrict__ Ms, int n, int H, int k) {
  __shared__ __align__(16) float As[16][68];
  __shared__ __align__(16) float Bs[16][68];
  __shared__ float hp[4][64];
  __shared__ float pp[4][64];
  __shared__ int gIdx[64];
  int tid = threadIdx.x;
  int i0 = blockIdx.x * 64, j0 = blockIdx.y * 64;
  if (tid < 64) gIdx[tid] = perm[i0 + tid];
  __syncthreads();
  int tx = tid & 15, ty = tid >> 4;
  int aI = tid & 63, aK = (tid >> 6) << 2;
  int gA = gIdx[aI];
  bool bok = (j0 + aI) < k;
  const float* bRow = P + (size_t)(j0 + (bok ? aI : 0)) * H;
  float acc[4][4] = {};
  float ha = 0.f, pa = 0.f;
  for (int k0 = 0; k0 < H; k0 += 16) {
    float4 av = *(const float4*)(h + (size_t)gA * H + k0 + aK);
    float4 bv = *(const float4*)(bRow + k0 + aK);
    ha += av.x * av.x + av.y * av.y + av.z * av.z + av.w * av.w;
    pa += bv.x * bv.x + bv.y * bv.y + bv.z * bv.z + bv.w * bv.w;
    __syncthreads();
    As[aK + 0][aI] = av.x; As[aK + 1][aI] = av.y; As[aK + 2][aI] = av.z; As[aK + 3][aI] = av.w;
    Bs[aK + 0][aI] = bv.x; Bs[aK + 1][aI] = bv.y; Bs[aK + 2][aI] = bv.z; Bs[aK + 3][aI] = bv.w;
    __syncthreads();
#pragma unroll
    for (int kk = 0; kk < 16; kk++) {
      float4 a4 = *(float4*)(&As[kk][ty << 2]);
      float4 b4 = *(float4*)(&Bs[kk][tx << 2]);
      float aa[4] = {a4.x, a4.y, a4.z, a4.w};
      float bb[4] = {b4.x, b4.y, b4.z, b4.w};
#pragma unroll
      for (int p = 0; p < 4; p++)
#pragma unroll
        for (int q = 0; q < 4; q++)
          acc[p][q] = fmaf(aa[p], bb[q], acc[p][q]);
    }
  }
  int grp = tid >> 6;
  hp[grp][aI] = ha;
  pp[grp][aI] = pa;
  __syncthreads();
#pragma unroll
  for (int p = 0; p < 4; p++) {
    int rr = (ty << 2) + p;
    int r = i0 + rr;
    float hq = hp[0][rr] + hp[1][rr] + hp[2][rr] + hp[3][rr];
#pragma unroll
    for (int q = 0; q < 4; q++) {
      int jl = (tx << 2) + q;
      int j = j0 + jl;
      if (j < k) {
        float pq = pp[0][jl] + pp[1][jl] + pp[2][jl] + pp[3][jl];
        float d2 = hq + pq - 2.f * acc[p][q];
        d2 = fmaxf(d2, 0.f);
        Ms[(size_t)r * k + j] = -d2 * MSCALE2;
      }
    }
  }
}

// Persistent Sinkhorn, LINEAR domain, ONE block per type (17 blocks). K' bf16:
// first LCAP rows resident in LDS, rest stream from L2. Column sums fully
// block-local. Only cross-block item: scalar Sigma-u, lagged, wave 15.
// R6: phase A reworked to unpack-once + packed f32x2 FMA (v_pk_fma_f32 path):
// each bf16 pair is unpacked to an f32x2 register ONCE and used by both the
// rs-dot and the colsum-acc -> ~2x fewer VALU ops, bit-identical results.
__global__ __launch_bounds__(1024) void k_sink(const float* __restrict__ Ms,
    unsigned short* __restrict__ Ms2, const int* __restrict__ meta,
    float* __restrict__ suD, unsigned* __restrict__ suE,
    float* __restrict__ uF, float* __restrict__ vF,
    int k, float tm_last) {
  __shared__ __align__(16) char Klds[LCAP * LROW];   // 136,448 B
  __shared__ __align__(16) float WP2[15][KP];        //  19,200 B
  __shared__ __align__(16) float V[KP];              //   1,280 B
  __shared__ float SU[15];
  __shared__ float w_sh;
  __shared__ int lvl_ep;
  int tid = threadIdx.x, lane = tid & 63, wv = tid >> 6;
  int t = blockIdx.x;            // 0..16, one type per block
  int myR = meta[t];
  int s0 = meta[32 + t];
  int ntF = (myR + 3) >> 2;      // tiles of 4 rows
  bool l2v = (lane + 64) < (k >> 2);   // fp32-prologue second-half lanes
  int g = lane >> 4, cg = lane & 15;   // row-in-quad, col-group
  bool r2a = (cg < 8);                 // cols 256..319 active lanes

  if (tid == 0) { w_sh = 1.f; lvl_ep = 0; }

  // ---- prologue pass 1: block-local colmax (waves 0..14) ----
  if (wv < 15) {
    float4 cm0 = make_float4(-3e38f, -3e38f, -3e38f, -3e38f);
    float4 cm1 = cm0;
    for (int tile = wv; tile < ntF; tile += 15) {
      int r0 = tile * 4;
#pragma unroll
      for (int rr = 0; rr < 4; rr++) {
        int rc = (r0 + rr < myR) ? (r0 + rr) : r0;
        const float4* rp = (const float4*)(Ms + (size_t)(s0 + rc) * k);
        float4 a0 = rp[lane];
        cm0.x = fmaxf(cm0.x, a0.x); cm0.y = fmaxf(cm0.y, a0.y);
        cm0.z = fmaxf(cm0.z, a0.z); cm0.w = fmaxf(cm0.w, a0.w);
        if (l2v) {
          float4 a1 = rp[lane + 64];
          cm1.x = fmaxf(cm1.x, a1.x); cm1.y = fmaxf(cm1.y, a1.y);
          cm1.z = fmaxf(cm1.z, a1.z); cm1.w = fmaxf(cm1.w, a1.w);
        }
      }
    }
    *(float4*)&WP2[wv][4 * lane] = cm0;
    if (l2v) *(float4*)&WP2[wv][4 * (lane + 64)] = cm1;
  }
  __syncthreads();
  if (tid < k) {
    float cmax = WP2[0][tid];
#pragma unroll
    for (int q = 1; q < 15; q++) cmax = fmaxf(cmax, WP2[q][tid]);
    V[tid] = cmax;
  }
  __syncthreads();
  // ---- pass 2: K' = 2^(M - cmax) -> bf16, to global Ms2 + LDS rows ----
  {
    float4 cx0 = *(const float4*)&V[4 * lane];
    float4 cx1 = l2v ? *(const float4*)&V[4 * (lane + 64)] : cx0;
    for (int tile = wv; tile < ntF; tile += 16) {
      int r0 = tile * 4;
#pragma unroll
      for (int rr = 0; rr < 4; rr++) {
        int r = r0 + rr;
        if (r < myR) {
          const float4* rp = (const float4*)(Ms + (size_t)(s0 + r) * k);
          char* orow = (char*)Ms2 + (size_t)(s0 + r) * (KP * 2);
          char* lrow = Klds + (size_t)r * LROW;
          bool inL = (r < LCAP);
          float4 a0 = rp[lane];
          uint2 o;
          o.x = bfp(EX2(a0.x - cx0.x), EX2(a0.y - cx0.y));
          o.y = bfp(EX2(a0.z - cx0.z), EX2(a0.w - cx0.w));
          *(uint2*)(orow + 8 * lane) = o;
          if (inL) *(uint2*)(lrow + 8 * lane) = o;
          if (l2v) {
            float4 a1 = rp[lane + 64];
            uint2 o1;
            o1.x = bfp(EX2(a1.x - cx1.x), EX2(a1.y - cx1.y));
            o1.y = bfp(EX2(a1.z - cx1.z), EX2(a1.w - cx1.w));
            *(uint2*)(orow + 512 + 8 * lane) = o1;
            if (inL) *(uint2*)(lrow + 512 + 8 * lane) = o1;
          } else if (lane < 16) {
            *(uint2*)(orow + 512 + 8 * lane) = make_uint2(0u, 0u);  // pad cols
            if (inL) *(uint2*)(lrow + 512 + 8 * lane) = make_uint2(0u, 0u);
          }
        }
      }
    }
  }
  __syncthreads();
  if (tid < KP) V[tid] = 0.f;  // v~ init (underflow-equivalent to reference)
  __syncthreads();

  for (int m = 0; m < NITER; m++) {
    int epoch = m + 1;
    int slot = m & 3;
    // ---- wave 15 (exchange-only): consume Sigma-u_{m-1} over 17 blocks ----
    if (wv == 15) {
      if (m > 0) {
        int pslot = (m - 1) & 3;
        unsigned want = (unsigned)m;
        bool need = lane < NB;
        for (;;) {
          bool ok = !need ||
              (__hip_atomic_load(&suE[(pslot * NB + lane) * 16],
                                 __ATOMIC_RELAXED, __HIP_MEMORY_SCOPE_AGENT) >= want);
          if (__all(ok)) break;
          __builtin_amdgcn_s_sleep(1);
        }
        float s = need
            ? __hip_atomic_load(&suD[(pslot * NB + lane) * 16],
                                __ATOMIC_RELAXED, __HIP_MEMORY_SCOPE_AGENT)
            : 0.f;
#pragma unroll
        for (int o = 32; o; o >>= 1) s += __shfl_xor(s, o);
        if (lane == 0) w_sh = tm_last / s;
      }
      if (lane == 0)
        __hip_atomic_store(&lvl_ep, epoch, __ATOMIC_RELEASE, __HIP_MEMORY_SCOPE_WORKGROUP);
    }
    // ---- phase A: LDS/L2-fed row pass, unpack-once + packed f32x2 FMA ----
    float w = 0.f;
    bool haveW = (wv == 15);
    float su = 0.f;
    f32x2 vv[3][4];
#pragma unroll
    for (int q3 = 0; q3 < 3; q3++) {
      if (q3 < 2 || r2a) {
#pragma unroll
        for (int d = 0; d < 4; d++)
          vv[q3][d] = *(const f32x2*)&V[q3 * 128 + cg * 8 + 2 * d];
      } else {
#pragma unroll
        for (int d = 0; d < 4; d++) vv[q3][d] = (f32x2)(0.f);
      }
    }
    f32x2 acc[3][4];
#pragma unroll
    for (int q3 = 0; q3 < 3; q3++)
#pragma unroll
      for (int d = 0; d < 4; d++) acc[q3][d] = (f32x2)(0.f);

    int t0 = (wv < 15) ? wv : ntF;   // wave 15 does no row work
    for (; t0 < ntF; t0 += 15 * CH) {
      f32x2 P[CH][3][4];
      float rs[CH];
      // -- rs pass: load tiles, unpack ONCE to f32x2, packed dot with v~ --
#pragma unroll
      for (int ccc = 0; ccc < CH; ccc++) {
        int tile = t0 + 15 * ccc;
        rs[ccc] = 0.f;
        if (tile < ntF) {
          int r = tile * 4 + g;
          int rc = (r < myR) ? r : (myR - 1);
          uint4 T[3];
          uint4 z4 = make_uint4(0u, 0u, 0u, 0u);
          if (rc < LCAP) {
            const uint4* lp = (const uint4*)(Klds + (size_t)rc * LROW + (cg << 4));
            T[0] = lp[0];
            T[1] = lp[16];
            T[2] = r2a ? lp[32] : z4;
          } else {
            const uint4* gp = (const uint4*)((const char*)Ms2 +
                (size_t)(s0 + rc) * (KP * 2) + (cg << 4));
            T[0] = gp[0];
            T[1] = gp[16];
            T[2] = r2a ? gp[32] : z4;
          }
#pragma unroll
          for (int q3 = 0; q3 < 3; q3++) {
            P[ccc][q3][0] = bf2up(T[q3].x);
            P[ccc][q3][1] = bf2up(T[q3].y);
            P[ccc][q3][2] = bf2up(T[q3].z);
            P[ccc][q3][3] = bf2up(T[q3].w);
          }
          f32x2 rp = (f32x2)(0.f);
#pragma unroll
          for (int q3 = 0; q3 < 3; q3++)
#pragma unroll
            for (int d = 0; d < 4; d++)
              rp = __builtin_elementwise_fma(P[ccc][q3][d], vv[q3][d], rp);
          float r1 = rp.x + rp.y;
          r1 += __shfl_xor(r1, 1); r1 += __shfl_xor(r1, 2);
          r1 += __shfl_xor(r1, 4); r1 += __shfl_xor(r1, 8);
          rs[ccc] = r1;
        }
      }
      // -- w gate (covered by the rs pass above; latches) --
      if (!haveW) {
        while (__hip_atomic_load(&lvl_ep, __ATOMIC_ACQUIRE, __HIP_MEMORY_SCOPE_WORKGROUP) < epoch)
          __builtin_amdgcn_s_sleep(1);
        w = w_sh;
        haveW = true;
      }
      // -- u / acc pass (unpacked pairs still in regs; packed FMA) --
#pragma unroll
      for (int ccc = 0; ccc < CH; ccc++) {
        int tile = t0 + 15 * ccc;
        if (tile < ntF) {
          int r = tile * 4 + g;
          bool valid = (r < myR);
          float u = RCP(rs[ccc] + w);
          float uu = valid ? u : 0.f;
          if (cg == 0) {
            su += uu;
            if (valid && m == NITER - 1) uF[s0 + r] = u;
          }
          f32x2 uup;
          uup.x = uu; uup.y = uu;
#pragma unroll
          for (int q3 = 0; q3 < 3; q3++)
#pragma unroll
            for (int d = 0; d < 4; d++)
              acc[q3][d] = __builtin_elementwise_fma(P[ccc][q3][d], uup, acc[q3][d]);
        }
      }
    }
    if (!haveW) {  // zero-tile waves still ratchet the epoch
      while (__hip_atomic_load(&lvl_ep, __ATOMIC_ACQUIRE, __HIP_MEMORY_SCOPE_WORKGROUP) < epoch)
        __builtin_amdgcn_s_sleep(1);
      haveW = true;
    }

    if (wv < 15) {
      // reduce colsum partials across the 4 row-groups, lanes 0..15 store
#pragma unroll
      for (int q3 = 0; q3 < 3; q3++)
#pragma unroll
        for (int d = 0; d < 4; d++) {
          float ax = acc[q3][d].x, ay = acc[q3][d].y;
          ax += __shfl_xor(ax, 16); ax += __shfl_xor(ax, 32);
          ay += __shfl_xor(ay, 16); ay += __shfl_xor(ay, 32);
          acc[q3][d].x = ax; acc[q3][d].y = ay;
        }
      if (lane < 16) {
#pragma unroll
        for (int q3 = 0; q3 < 3; q3++) {
          if (q3 < 2 || lane < 8) {
            *(float4*)&WP2[wv][q3 * 128 + lane * 8] =
                make_float4(acc[q3][0].x, acc[q3][0].y, acc[q3][1].x, acc[q3][1].y);
            *(float4*)&WP2[wv][q3 * 128 + lane * 8 + 4] =
                make_float4(acc[q3][2].x, acc[q3][2].y, acc[q3][3].x, acc[q3][3].y);
          }
        }
      }
      float sr = su;
      sr += __shfl_xor(sr, 16);
      sr += __shfl_xor(sr, 32);
      if (lane == 0) SU[wv] = sr;
    }
    __syncthreads();
    // ---- phase B: block-local colsum -> v~; publish Sigma-u for next iter ----
    if (tid < KP) {
      float s = WP2[0][tid];
#pragma unroll
      for (int q = 1; q < 15; q++) s += WP2[q][tid];
      V[tid] = (tid < k) ? RCP(s) : 0.f;
    }
    if (wv == 15) {
      float sp = (lane < 15) ? SU[lane] : 0.f;
#pragma unroll
      for (int o = 32; o; o >>= 1) sp += __shfl_xor(sp, o);
      if (lane == 0)
        __hip_atomic_store(&suD[(slot * NB + t) * 16], sp,
                           __ATOMIC_RELAXED, __HIP_MEMORY_SCOPE_AGENT);
      __builtin_amdgcn_s_waitcnt(0);
      if (lane == 0)
        __hip_atomic_store(&suE[(slot * NB + t) * 16], (unsigned)epoch,
                           __ATOMIC_RELAXED, __HIP_MEMORY_SCOPE_AGENT);
    }
    __syncthreads();
  }
  for (int j = tid; j < k; j += 1024) vF[(size_t)t * k + j] = V[j];
}

// epilogue (linear): T_rj = K'_rj·u_r·v~_j; logits = ln(T+1e-8); T scatter with
// incremental mod-17 and NONTEMPORAL stores (write-only output). K' read bf16.
__global__ __launch_bounds__(256) void k_epi(const unsigned short* __restrict__ Ms2,
    const float* __restrict__ uF, const float* __restrict__ vF,
    const int* __restrict__ perm, const int* __restrict__ tys,
    float* __restrict__ out, int n, int k) {
  __shared__ float vals[KCAP];
  int r = blockIdx.x;
  int i = perm[r], t = tys[r];
  float u = uF[r];
  const unsigned short* Krow = Ms2 + (size_t)r * KP;
  const float* Vrow = vF + (size_t)t * k;
  for (int j = threadIdx.x; j < k; j += 256)
    vals[j] = __uint_as_float((unsigned)Krow[j] << 16) * u * Vrow[j];
  __syncthreads();
  float* lg = out + (size_t)i * k;
  for (int j = threadIdx.x; j < k; j += 256)
    __builtin_nontemporal_store(LG2(vals[j] + 1e-8f) * 0.6931471805599453f, &lg[j]);
  int ns = k * NT;
  float* Trow = out + (size_t)n * k + (size_t)i * ns;
  if ((ns & 3) == 0) {
    int n4 = ns >> 2;
    int o0 = threadIdx.x << 2;
    int rmod = o0 % NT;
    for (int g4 = threadIdx.x; g4 < n4; g4 += 256, o0 += 1024) {
      int sstar = t - rmod; if (sstar < 0) sstar += NT;
      int j = (unsigned)(o0 + sstar) / (unsigned)NT;
      float vv = vals[j < k ? j : 0];
      vfloat4 v;
      v.x = (sstar == 0) ? vv : 0.f;
      v.y = (sstar == 1) ? vv : 0.f;
      v.z = (sstar == 2) ? vv : 0.f;
      v.w = (sstar == 3) ? vv : 0.f;
      __builtin_nontemporal_store(v, (vfloat4*)(Trow + o0));
      rmod += 4; if (rmod >= NT) rmod -= NT;
    }
  } else {
    for (int o = threadIdx.x; o < ns; o += 256) {
      int j = o / NT;
      int tt = o - j * NT;
      Trow[o] = (tt == t) ? vals[j] : 0.f;
    }
  }
}

extern "C" void kernel_launch(void* const* d_in, const int* in_sizes, int n_in,
                              void* d_out, int out_size, void* d_ws, size_t ws_size,
                              hipStream_t stream) {
  const float* emb = (const float*)d_in[0];
  const float* W1  = (const float*)d_in[1];
  const float* b1  = (const float*)d_in[2];
  const float* P   = (const float*)d_in[3];
  const int*   jt  = (const int*)d_in[4];
  (void)n_in; (void)ws_size;

  const int n = in_sizes[4];
  const int H = in_sizes[2];
  const int D = in_sizes[1] / H;
  const int k = out_size / (n * (NT + 1));
  const int nslots = k * NT;
  const float tm_last = (float)((n - nslots) > 1 ? (n - nslots) : 1);

  char* w = (char*)d_ws;
  size_t off = 0;
  auto take = [&](size_t bytes) -> char* {
    char* p = w + off;
    off = (off + bytes + 255) & ~(size_t)255;
    return p;
  };
  int*      meta = (int*)take(4096);
  int*      perm = (int*)take((size_t)n * 4);
  int*      tys  = (int*)take((size_t)n * 4);
  float*    h    = (float*)take((size_t)n * H * 4);
  float*    Ms   = (float*)take((size_t)n * k * 4);
  unsigned short* Ms2 = (unsigned short*)take((size_t)n * KP * 2 + 1024);
  float*    suD  = (float*)take((size_t)4 * NB * 64);
  unsigned* suE  = (unsigned*)take((size_t)4 * NB * 64);
  float*    uF   = (float*)take((size_t)n * 4);
  float*    vF   = (float*)take((size_t)NT * k * 4);

  (void)hipMemsetAsync(suE, 0, (size_t)4 * NB * 64, stream);
  k_bucket<<<1, 1024, 0, stream>>>(jt, n, meta, perm, tys);
  k_hgemm<<<dim3(n / 64, H / 64), dim3(256), 0, stream>>>(emb, W1, b1, h, n, D, H);
  k_msort<<<dim3(n / 64, (k + 63) / 64), dim3(256), 0, stream>>>(h, P, perm, Ms, n, H, k);
  k_sink<<<NB, 1024, 0, stream>>>(Ms, Ms2, meta, suD, suE, uF, vF, k, tm_last);
  k_epi<<<n, 256, 0, stream>>>(Ms2, uF, vF, perm, tys, (float*)d_out, n, k);
}

// Round 7
// 546.974 us; speedup vs baseline: 1.0289x; 1.0289x over previous
//
#include <hip/hip_runtime.h>
#include <math.h>

#define NT 17
#define NB 17       // one block per type
#define KCAP 300
#define KP 320      // padded column count for bf16 K' rows (640 B/row in global)
#define LROW 656    // LDS row stride bytes (16B-aligned, 656/4%32=4 breaks bank alias)
#define LCAP 208    // K' rows resident in LDS per block (spill -> global Ms2)
#define CH 1        // tiles per register chunk (CH=2 spilled: 128-VGPR cap @1024thr)
#define NITER 30
// -1/tau * log2(e): M matrix is in base-2 log domain
#define MSCALE2 28.853900817779268f

typedef unsigned long long u64;
typedef float vfloat4 __attribute__((ext_vector_type(4)));
typedef float f32x2 __attribute__((ext_vector_type(2)));

#define EX2(x) __builtin_amdgcn_exp2f(x)
#define LG2(x) __builtin_amdgcn_logf(x)
#if __has_builtin(__builtin_amdgcn_rcpf)
#define RCP(x) __builtin_amdgcn_rcpf(x)
#else
#define RCP(x) (1.0f / (x))
#endif

// bf16 round-to-nearest-even pack helpers
__device__ inline unsigned bf16rne(float x) {
  unsigned u = __float_as_uint(x);
  return (u + 0x7FFFu + ((u >> 16) & 1u)) >> 16;
}
__device__ inline unsigned bfp(float lo, float hi) {
  return bf16rne(lo) | (bf16rne(hi) << 16);
}
#define BFLO(p) __uint_as_float((p) << 16)
#define BFHI(p) __uint_as_float((p) & 0xFFFF0000u)

// unpack a dword of 2 bf16 into an f32x2 (for v_pk_fma_f32 feeding)
__device__ inline f32x2 bf2up(unsigned u) {
  f32x2 r;
  r.x = BFLO(u);
  r.y = BFHI(u);
  return r;
}

// ---- meta layout ----
// [0..16]   typeCount
// [32..48]  typeOff

__device__ inline float selu_f(float x) {
  const float scale = 1.0507009873554804934193349852946f;
  const float alpha = 1.6732632423543772848170429916717f;
  return x > 0.f ? scale * x : scale * alpha * (EX2(x * 1.4426950408889634f) - 1.f);
}

// fused histogram + prefix + scatter (single block)
__global__ __launch_bounds__(1024) void k_bucket(const int* __restrict__ jt, int n,
    int* __restrict__ meta, int* __restrict__ perm, int* __restrict__ tys) {
  __shared__ int hist[NT];
  __shared__ int off[NT];
  __shared__ int cnt[NT];
  int tid = threadIdx.x;
  if (tid < NT) { hist[tid] = 0; cnt[tid] = 0; }
  __syncthreads();
  for (int i = tid; i < n; i += 1024) atomicAdd(&hist[jt[i]], 1);
  __syncthreads();
  if (tid == 0) {
    int o = 0;
    for (int t = 0; t < NT; t++) {
      off[t] = o; meta[32 + t] = o; meta[t] = hist[t]; o += hist[t];
    }
  }
  __syncthreads();
  for (int i = tid; i < n; i += 1024) {
    int t = jt[i];
    int pos = off[t] + atomicAdd(&cnt[t], 1);
    perm[pos] = i;
    tys[pos] = t;
  }
}

// h = selu(emb @ W1 + b1)   (n x D) @ (D x H)
__global__ __launch_bounds__(256) void k_hgemm(const float* __restrict__ A,
    const float* __restrict__ B, const float* __restrict__ bias,
    float* __restrict__ C, int n, int D, int H) {
  __shared__ __align__(16) float As[16][68];
  __shared__ __align__(16) float Bs[16][68];
  int tid = threadIdx.x;
  int i0 = blockIdx.x * 64, j0 = blockIdx.y * 64;
  int tx = tid & 15, ty = tid >> 4;
  int aI = tid & 63, aK = (tid >> 6) << 2;
  int bJ = (tid & 15) << 2, bK = tid >> 4;
  float acc[4][4] = {};
  for (int k0 = 0; k0 < D; k0 += 16) {
    float4 av = *(const float4*)(A + (size_t)(i0 + aI) * D + k0 + aK);
    float4 bv = *(const float4*)(B + (size_t)(k0 + bK) * H + j0 + bJ);
    __syncthreads();
    As[aK + 0][aI] = av.x; As[aK + 1][aI] = av.y; As[aK + 2][aI] = av.z; As[aK + 3][aI] = av.w;
    *(float4*)(&Bs[bK][bJ]) = bv;
    __syncthreads();
#pragma unroll
    for (int kk = 0; kk < 16; kk++) {
      float4 a4 = *(float4*)(&As[kk][ty << 2]);
      float4 b4 = *(float4*)(&Bs[kk][tx << 2]);
      float aa[4] = {a4.x, a4.y, a4.z, a4.w};
      float bb[4] = {b4.x, b4.y, b4.z, b4.w};
#pragma unroll
      for (int p = 0; p < 4; p++)
#pragma unroll
        for (int q = 0; q < 4; q++)
          acc[p][q] = fmaf(aa[p], bb[q], acc[p][q]);
    }
  }
#pragma unroll
  for (int p = 0; p < 4; p++) {
    int i = i0 + (ty << 2) + p;
    float o[4];
#pragma unroll
    for (int q = 0; q < 4; q++) {
      int j = j0 + (tx << 2) + q;
      o[q] = selu_f(acc[p][q] + bias[j]);
    }
    *(float4*)(C + (size_t)i * H + j0 + (tx << 2)) = make_float4(o[0], o[1], o[2], o[3]);
  }
}

// Ms[r][j] = -max(0, |h_r|^2+|p_j|^2-2*dot)/tau*log2e, rows type-sorted.
__global__ __launch_bounds__(256) void k_msort(const float* __restrict__ h,
    const float* __restrict__ P, const int* __restrict__ perm,
    float* __restrict__ Ms, int n, int H, int k) {
  __shared__ __align__(16) float As[16][68];
  __shared__ __align__(16) float Bs[16][68];
  __shared__ float hp[4][64];
  __shared__ float pp[4][64];
  __shared__ int gIdx[64];
  int tid = threadIdx.x;
  int i0 = blockIdx.x * 64, j0 = blockIdx.y * 64;
  if (tid < 64) gIdx[tid] = perm[i0 + tid];
  __syncthreads();
  int tx = tid & 15, ty = tid >> 4;
  int aI = tid & 63, aK = (tid >> 6) << 2;
  int gA = gIdx[aI];
  bool bok = (j0 + aI) < k;
  const float* bRow = P + (size_t)(j0 + (bok ? aI : 0)) * H;
  float acc[4][4] = {};
  float ha = 0.f, pa = 0.f;
  for (int k0 = 0; k0 < H; k0 += 16) {
    float4 av = *(const float4*)(h + (size_t)gA * H + k0 + aK);
    float4 bv = *(const float4*)(bRow + k0 + aK);
    ha += av.x * av.x + av.y * av.y + av.z * av.z + av.w * av.w;
    pa += bv.x * bv.x + bv.y * bv.y + bv.z * bv.z + bv.w * bv.w;
    __syncthreads();
    As[aK + 0][aI] = av.x; As[aK + 1][aI] = av.y; As[aK + 2][aI] = av.z; As[aK + 3][aI] = av.w;
    Bs[aK + 0][aI] = bv.x; Bs[aK + 1][aI] = bv.y; Bs[aK + 2][aI] = bv.z; Bs[aK + 3][aI] = bv.w;
    __syncthreads();
#pragma unroll
    for (int kk = 0; kk < 16; kk++) {
      float4 a4 = *(float4*)(&As[kk][ty << 2]);
      float4 b4 = *(float4*)(&Bs[kk][tx << 2]);
      float aa[4] = {a4.x, a4.y, a4.z, a4.w};
      float bb[4] = {b4.x, b4.y, b4.z, b4.w};
#pragma unroll
      for (int p = 0; p < 4; p++)
#pragma unroll
        for (int q = 0; q < 4; q++)
          acc[p][q] = fmaf(aa[p], bb[q], acc[p][q]);
    }
  }
  int grp = tid >> 6;
  hp[grp][aI] = ha;
  pp[grp][aI] = pa;
  __syncthreads();
#pragma unroll
  for (int p = 0; p < 4; p++) {
    int rr = (ty << 2) + p;
    int r = i0 + rr;
    float hq = hp[0][rr] + hp[1][rr] + hp[2][rr] + hp[3][rr];
#pragma unroll
    for (int q = 0; q < 4; q++) {
      int jl = (tx << 2) + q;
      int j = j0 + jl;
      if (j < k) {
        float pq = pp[0][jl] + pp[1][jl] + pp[2][jl] + pp[3][jl];
        float d2 = hq + pq - 2.f * acc[p][q];
        d2 = fmaxf(d2, 0.f);
        Ms[(size_t)r * k + j] = -d2 * MSCALE2;
      }
    }
  }
}

// Persistent Sinkhorn, LINEAR domain, ONE block per type (17 blocks). K' bf16:
// first LCAP rows resident in LDS, rest stream from L2. Column sums fully
// block-local. Only cross-block item: scalar Sigma-u, lagged, wave 15.
// R7: unpack-once + packed f32x2 FMA with CH=1 so the live tile fits the
// 128-VGPR cap (CH=2 spilled to scratch in R6: VALUBusy down, WRITE_SIZE up).
__global__ __launch_bounds__(1024) void k_sink(const float* __restrict__ Ms,
    unsigned short* __restrict__ Ms2, const int* __restrict__ meta,
    float* __restrict__ suD, unsigned* __restrict__ suE,
    float* __restrict__ uF, float* __restrict__ vF,
    int k, float tm_last) {
  __shared__ __align__(16) char Klds[LCAP * LROW];   // 136,448 B
  __shared__ __align__(16) float WP2[15][KP];        //  19,200 B
  __shared__ __align__(16) float V[KP];              //   1,280 B
  __shared__ float SU[15];
  __shared__ float w_sh;
  __shared__ int lvl_ep;
  int tid = threadIdx.x, lane = tid & 63, wv = tid >> 6;
  int t = blockIdx.x;            // 0..16, one type per block
  int myR = meta[t];
  int s0 = meta[32 + t];
  int ntF = (myR + 3) >> 2;      // tiles of 4 rows
  bool l2v = (lane + 64) < (k >> 2);   // fp32-prologue second-half lanes
  int g = lane >> 4, cg = lane & 15;   // row-in-quad, col-group
  bool r2a = (cg < 8);                 // cols 256..319 active lanes

  if (tid == 0) { w_sh = 1.f; lvl_ep = 0; }

  // ---- prologue pass 1: block-local colmax (waves 0..14) ----
  if (wv < 15) {
    float4 cm0 = make_float4(-3e38f, -3e38f, -3e38f, -3e38f);
    float4 cm1 = cm0;
    for (int tile = wv; tile < ntF; tile += 15) {
      int r0 = tile * 4;
#pragma unroll
      for (int rr = 0; rr < 4; rr++) {
        int rc = (r0 + rr < myR) ? (r0 + rr) : r0;
        const float4* rp = (const float4*)(Ms + (size_t)(s0 + rc) * k);
        float4 a0 = rp[lane];
        cm0.x = fmaxf(cm0.x, a0.x); cm0.y = fmaxf(cm0.y, a0.y);
        cm0.z = fmaxf(cm0.z, a0.z); cm0.w = fmaxf(cm0.w, a0.w);
        if (l2v) {
          float4 a1 = rp[lane + 64];
          cm1.x = fmaxf(cm1.x, a1.x); cm1.y = fmaxf(cm1.y, a1.y);
          cm1.z = fmaxf(cm1.z, a1.z); cm1.w = fmaxf(cm1.w, a1.w);
        }
      }
    }
    *(float4*)&WP2[wv][4 * lane] = cm0;
    if (l2v) *(float4*)&WP2[wv][4 * (lane + 64)] = cm1;
  }
  __syncthreads();
  if (tid < k) {
    float cmax = WP2[0][tid];
#pragma unroll
    for (int q = 1; q < 15; q++) cmax = fmaxf(cmax, WP2[q][tid]);
    V[tid] = cmax;
  }
  __syncthreads();
  // ---- pass 2: K' = 2^(M - cmax) -> bf16, to global Ms2 + LDS rows ----
  {
    float4 cx0 = *(const float4*)&V[4 * lane];
    float4 cx1 = l2v ? *(const float4*)&V[4 * (lane + 64)] : cx0;
    for (int tile = wv; tile < ntF; tile += 16) {
      int r0 = tile * 4;
#pragma unroll
      for (int rr = 0; rr < 4; rr++) {
        int r = r0 + rr;
        if (r < myR) {
          const float4* rp = (const float4*)(Ms + (size_t)(s0 + r) * k);
          char* orow = (char*)Ms2 + (size_t)(s0 + r) * (KP * 2);
          char* lrow = Klds + (size_t)r * LROW;
          bool inL = (r < LCAP);
          float4 a0 = rp[lane];
          uint2 o;
          o.x = bfp(EX2(a0.x - cx0.x), EX2(a0.y - cx0.y));
          o.y = bfp(EX2(a0.z - cx0.z), EX2(a0.w - cx0.w));
          *(uint2*)(orow + 8 * lane) = o;
          if (inL) *(uint2*)(lrow + 8 * lane) = o;
          if (l2v) {
            float4 a1 = rp[lane + 64];
            uint2 o1;
            o1.x = bfp(EX2(a1.x - cx1.x), EX2(a1.y - cx1.y));
            o1.y = bfp(EX2(a1.z - cx1.z), EX2(a1.w - cx1.w));
            *(uint2*)(orow + 512 + 8 * lane) = o1;
            if (inL) *(uint2*)(lrow + 512 + 8 * lane) = o1;
          } else if (lane < 16) {
            *(uint2*)(orow + 512 + 8 * lane) = make_uint2(0u, 0u);  // pad cols
            if (inL) *(uint2*)(lrow + 512 + 8 * lane) = make_uint2(0u, 0u);
          }
        }
      }
    }
  }
  __syncthreads();
  if (tid < KP) V[tid] = 0.f;  // v~ init (underflow-equivalent to reference)
  __syncthreads();

  for (int m = 0; m < NITER; m++) {
    int epoch = m + 1;
    int slot = m & 3;
    // ---- wave 15 (exchange-only): consume Sigma-u_{m-1} over 17 blocks ----
    if (wv == 15) {
      if (m > 0) {
        int pslot = (m - 1) & 3;
        unsigned want = (unsigned)m;
        bool need = lane < NB;
        for (;;) {
          bool ok = !need ||
              (__hip_atomic_load(&suE[(pslot * NB + lane) * 16],
                                 __ATOMIC_RELAXED, __HIP_MEMORY_SCOPE_AGENT) >= want);
          if (__all(ok)) break;
          __builtin_amdgcn_s_sleep(1);
        }
        float s = need
            ? __hip_atomic_load(&suD[(pslot * NB + lane) * 16],
                                __ATOMIC_RELAXED, __HIP_MEMORY_SCOPE_AGENT)
            : 0.f;
#pragma unroll
        for (int o = 32; o; o >>= 1) s += __shfl_xor(s, o);
        if (lane == 0) w_sh = tm_last / s;
      }
      if (lane == 0)
        __hip_atomic_store(&lvl_ep, epoch, __ATOMIC_RELEASE, __HIP_MEMORY_SCOPE_WORKGROUP);
    }
    // ---- phase A: LDS/L2-fed row pass, unpack-once + packed f32x2 FMA ----
    float w = 0.f;
    bool haveW = (wv == 15);
    float su = 0.f;
    f32x2 vv[3][4];
#pragma unroll
    for (int q3 = 0; q3 < 3; q3++) {
      if (q3 < 2 || r2a) {
#pragma unroll
        for (int d = 0; d < 4; d++)
          vv[q3][d] = *(const f32x2*)&V[q3 * 128 + cg * 8 + 2 * d];
      } else {
#pragma unroll
        for (int d = 0; d < 4; d++) vv[q3][d] = (f32x2)(0.f);
      }
    }
    f32x2 acc[3][4];
#pragma unroll
    for (int q3 = 0; q3 < 3; q3++)
#pragma unroll
      for (int d = 0; d < 4; d++) acc[q3][d] = (f32x2)(0.f);

    int t0 = (wv < 15) ? wv : ntF;   // wave 15 does no row work
    for (; t0 < ntF; t0 += 15) {
      f32x2 P[3][4];
      // -- load tile, unpack ONCE to f32x2, packed dot with v~ --
      int r = t0 * 4 + g;
      int rc = (r < myR) ? r : (myR - 1);
      {
        uint4 T[3];
        uint4 z4 = make_uint4(0u, 0u, 0u, 0u);
        if (rc < LCAP) {
          const uint4* lp = (const uint4*)(Klds + (size_t)rc * LROW + (cg << 4));
          T[0] = lp[0];
          T[1] = lp[16];
          T[2] = r2a ? lp[32] : z4;
        } else {
          const uint4* gp = (const uint4*)((const char*)Ms2 +
              (size_t)(s0 + rc) * (KP * 2) + (cg << 4));
          T[0] = gp[0];
          T[1] = gp[16];
          T[2] = r2a ? gp[32] : z4;
        }
#pragma unroll
        for (int q3 = 0; q3 < 3; q3++) {
          P[q3][0] = bf2up(T[q3].x);
          P[q3][1] = bf2up(T[q3].y);
          P[q3][2] = bf2up(T[q3].z);
          P[q3][3] = bf2up(T[q3].w);
        }
      }
      f32x2 rp = (f32x2)(0.f);
#pragma unroll
      for (int q3 = 0; q3 < 3; q3++)
#pragma unroll
        for (int d = 0; d < 4; d++)
          rp = __builtin_elementwise_fma(P[q3][d], vv[q3][d], rp);
      float r1 = rp.x + rp.y;
      r1 += __shfl_xor(r1, 1); r1 += __shfl_xor(r1, 2);
      r1 += __shfl_xor(r1, 4); r1 += __shfl_xor(r1, 8);
      // -- w gate (first tile only; latches) --
      if (!haveW) {
        while (__hip_atomic_load(&lvl_ep, __ATOMIC_ACQUIRE, __HIP_MEMORY_SCOPE_WORKGROUP) < epoch)
          __builtin_amdgcn_s_sleep(1);
        w = w_sh;
        haveW = true;
      }
      // -- u / acc (unpacked pairs still in regs; packed FMA) --
      bool valid = (r < myR);
      float u = RCP(r1 + w);
      float uu = valid ? u : 0.f;
      if (cg == 0) {
        su += uu;
        if (valid && m == NITER - 1) uF[s0 + r] = u;
      }
      f32x2 uup;
      uup.x = uu; uup.y = uu;
#pragma unroll
      for (int q3 = 0; q3 < 3; q3++)
#pragma unroll
        for (int d = 0; d < 4; d++)
          acc[q3][d] = __builtin_elementwise_fma(P[q3][d], uup, acc[q3][d]);
    }
    if (!haveW) {  // zero-tile waves still ratchet the epoch
      while (__hip_atomic_load(&lvl_ep, __ATOMIC_ACQUIRE, __HIP_MEMORY_SCOPE_WORKGROUP) < epoch)
        __builtin_amdgcn_s_sleep(1);
      haveW = true;
    }

    if (wv < 15) {
      // reduce colsum partials across the 4 row-groups, lanes 0..15 store
#pragma unroll
      for (int q3 = 0; q3 < 3; q3++)
#pragma unroll
        for (int d = 0; d < 4; d++) {
          float ax = acc[q3][d].x, ay = acc[q3][d].y;
          ax += __shfl_xor(ax, 16); ax += __shfl_xor(ax, 32);
          ay += __shfl_xor(ay, 16); ay += __shfl_xor(ay, 32);
          acc[q3][d].x = ax; acc[q3][d].y = ay;
        }
      if (lane < 16) {
#pragma unroll
        for (int q3 = 0; q3 < 3; q3++) {
          if (q3 < 2 || lane < 8) {
            *(float4*)&WP2[wv][q3 * 128 + lane * 8] =
                make_float4(acc[q3][0].x, acc[q3][0].y, acc[q3][1].x, acc[q3][1].y);
            *(float4*)&WP2[wv][q3 * 128 + lane * 8 + 4] =
                make_float4(acc[q3][2].x, acc[q3][2].y, acc[q3][3].x, acc[q3][3].y);
          }
        }
      }
      float sr = su;
      sr += __shfl_xor(sr, 16);
      sr += __shfl_xor(sr, 32);
      if (lane == 0) SU[wv] = sr;
    }
    __syncthreads();
    // ---- phase B: block-local colsum -> v~; publish Sigma-u for next iter ----
    if (tid < KP) {
      float s = WP2[0][tid];
#pragma unroll
      for (int q = 1; q < 15; q++) s += WP2[q][tid];
      V[tid] = (tid < k) ? RCP(s) : 0.f;
    }
    if (wv == 15) {
      float sp = (lane < 15) ? SU[lane] : 0.f;
#pragma unroll
      for (int o = 32; o; o >>= 1) sp += __shfl_xor(sp, o);
      if (lane == 0)
        __hip_atomic_store(&suD[(slot * NB + t) * 16], sp,
                           __ATOMIC_RELAXED, __HIP_MEMORY_SCOPE_AGENT);
      __builtin_amdgcn_s_waitcnt(0);
      if (lane == 0)
        __hip_atomic_store(&suE[(slot * NB + t) * 16], (unsigned)epoch,
                           __ATOMIC_RELAXED, __HIP_MEMORY_SCOPE_AGENT);
    }
    __syncthreads();
  }
  for (int j = tid; j < k; j += 1024) vF[(size_t)t * k + j] = V[j];
}

// epilogue (linear): T_rj = K'_rj·u_r·v~_j; logits = ln(T+1e-8); T scatter with
// incremental mod-17 and NONTEMPORAL stores (write-only output). K' read bf16.
__global__ __launch_bounds__(256) void k_epi(const unsigned short* __restrict__ Ms2,
    const float* __restrict__ uF, const float* __restrict__ vF,
    const int* __restrict__ perm, const int* __restrict__ tys,
    float* __restrict__ out, int n, int k) {
  __shared__ float vals[KCAP];
  int r = blockIdx.x;
  int i = perm[r], t = tys[r];
  float u = uF[r];
  const unsigned short* Krow = Ms2 + (size_t)r * KP;
  const float* Vrow = vF + (size_t)t * k;
  for (int j = threadIdx.x; j < k; j += 256)
    vals[j] = __uint_as_float((unsigned)Krow[j] << 16) * u * Vrow[j];
  __syncthreads();
  float* lg = out + (size_t)i * k;
  for (int j = threadIdx.x; j < k; j += 256)
    __builtin_nontemporal_store(LG2(vals[j] + 1e-8f) * 0.6931471805599453f, &lg[j]);
  int ns = k * NT;
  float* Trow = out + (size_t)n * k + (size_t)i * ns;
  if ((ns & 3) == 0) {
    int n4 = ns >> 2;
    int o0 = threadIdx.x << 2;
    int rmod = o0 % NT;
    for (int g4 = threadIdx.x; g4 < n4; g4 += 256, o0 += 1024) {
      int sstar = t - rmod; if (sstar < 0) sstar += NT;
      int j = (unsigned)(o0 + sstar) / (unsigned)NT;
      float vv = vals[j < k ? j : 0];
      vfloat4 v;
      v.x = (sstar == 0) ? vv : 0.f;
      v.y = (sstar == 1) ? vv : 0.f;
      v.z = (sstar == 2) ? vv : 0.f;
      v.w = (sstar == 3) ? vv : 0.f;
      __builtin_nontemporal_store(v, (vfloat4*)(Trow + o0));
      rmod += 4; if (rmod >= NT) rmod -= NT;
    }
  } else {
    for (int o = threadIdx.x; o < ns; o += 256) {
      int j = o / NT;
      int tt = o - j * NT;
      Trow[o] = (tt == t) ? vals[j] : 0.f;
    }
  }
}

extern "C" void kernel_launch(void* const* d_in, const int* in_sizes, int n_in,
                              void* d_out, int out_size, void* d_ws, size_t ws_size,
                              hipStream_t stream) {
  const float* emb = (const float*)d_in[0];
  const float* W1  = (const float*)d_in[1];
  const float* b1  = (const float*)d_in[2];
  const float* P   = (const float*)d_in[3];
  const int*   jt  = (const int*)d_in[4];
  (void)n_in; (void)ws_size;

  const int n = in_sizes[4];
  const int H = in_sizes[2];
  const int D = in_sizes[1] / H;
  const int k = out_size / (n * (NT + 1));
  const int nslots = k * NT;
  const float tm_last = (float)((n - nslots) > 1 ? (n - nslots) : 1);

  char* w = (char*)d_ws;
  size_t off = 0;
  auto take = [&](size_t bytes) -> char* {
    char* p = w + off;
    off = (off + bytes + 255) & ~(size_t)255;
    return p;
  };
  int*      meta = (int*)take(4096);
  int*      perm = (int*)take((size_t)n * 4);
  int*      tys  = (int*)take((size_t)n * 4);
  float*    h    = (float*)take((size_t)n * H * 4);
  float*    Ms   = (float*)take((size_t)n * k * 4);
  unsigned short* Ms2 = (unsigned short*)take((size_t)n * KP * 2 + 1024);
  float*    suD  = (float*)take((size_t)4 * NB * 64);
  unsigned* suE  = (unsigned*)take((size_t)4 * NB * 64);
  float*    uF   = (float*)take((size_t)n * 4);
  float*    vF   = (float*)take((size_t)NT * k * 4);

  (void)hipMemsetAsync(suE, 0, (size_t)4 * NB * 64, stream);
  k_bucket<<<1, 1024, 0, stream>>>(jt, n, meta, perm, tys);
  k_hgemm<<<dim3(n / 64, H / 64), dim3(256), 0, stream>>>(emb, W1, b1, h, n, D, H);
  k_msort<<<dim3(n / 64, (k + 63) / 64), dim3(256), 0, stream>>>(h, P, perm, Ms, n, H, k);
  k_sink<<<NB, 1024, 0, stream>>>(Ms, Ms2, meta, suD, suE, uF, vF, k, tm_last);
  k_epi<<<n, 256, 0, stream>>>(Ms2, uF, vF, perm, tys, (float*)d_out, n, k);
}

// Round 8
// 422.055 us; speedup vs baseline: 1.3335x; 1.2960x over previous
//
#include <hip/hip_runtime.h>
#include <math.h>

#define NT 17
#define NBLK 34     // two blocks per type
#define KCAP 300
#define KP 320      // padded column count for bf16 K' rows (640 B/row in global)
#define LROW 656    // LDS row stride bytes (164 words % 32 banks = 4 -> no quad alias)
#define LCAP 200    // K' rows resident in LDS per block (spill -> global Ms2)
#define CH 2        // tiles (of 4 rows) per register chunk
#define NITER 30
// -1/tau * log2(e): M matrix is in base-2 log domain
#define MSCALE2 28.853900817779268f

typedef unsigned long long u64;
typedef float vfloat4 __attribute__((ext_vector_type(4)));

#define EX2(x) __builtin_amdgcn_exp2f(x)
#define LG2(x) __builtin_amdgcn_logf(x)
#if __has_builtin(__builtin_amdgcn_rcpf)
#define RCP(x) __builtin_amdgcn_rcpf(x)
#else
#define RCP(x) (1.0f / (x))
#endif

// bf16 round-to-nearest-even pack helpers
__device__ inline unsigned bf16rne(float x) {
  unsigned u = __float_as_uint(x);
  return (u + 0x7FFFu + ((u >> 16) & 1u)) >> 16;
}
__device__ inline unsigned bfp(float lo, float hi) {
  return bf16rne(lo) | (bf16rne(hi) << 16);
}
#define BFLO(p) __uint_as_float((p) << 16)
#define BFHI(p) __uint_as_float((p) & 0xFFFF0000u)

// ---- meta layout ----
// [0..16]   typeCount
// [32..48]  typeOff

__device__ inline float selu_f(float x) {
  const float scale = 1.0507009873554804934193349852946f;
  const float alpha = 1.6732632423543772848170429916717f;
  return x > 0.f ? scale * x : scale * alpha * (EX2(x * 1.4426950408889634f) - 1.f);
}

// fused histogram + prefix + scatter (single block)
__global__ __launch_bounds__(1024) void k_bucket(const int* __restrict__ jt, int n,
    int* __restrict__ meta, int* __restrict__ perm, int* __restrict__ tys) {
  __shared__ int hist[NT];
  __shared__ int off[NT];
  __shared__ int cnt[NT];
  int tid = threadIdx.x;
  if (tid < NT) { hist[tid] = 0; cnt[tid] = 0; }
  __syncthreads();
  for (int i = tid; i < n; i += 1024) atomicAdd(&hist[jt[i]], 1);
  __syncthreads();
  if (tid == 0) {
    int o = 0;
    for (int t = 0; t < NT; t++) {
      off[t] = o; meta[32 + t] = o; meta[t] = hist[t]; o += hist[t];
    }
  }
  __syncthreads();
  for (int i = tid; i < n; i += 1024) {
    int t = jt[i];
    int pos = off[t] + atomicAdd(&cnt[t], 1);
    perm[pos] = i;
    tys[pos] = t;
  }
}

// h = selu(emb @ W1 + b1)   (n x D) @ (D x H)
__global__ __launch_bounds__(256) void k_hgemm(const float* __restrict__ A,
    const float* __restrict__ B, const float* __restrict__ bias,
    float* __restrict__ C, int n, int D, int H) {
  __shared__ __align__(16) float As[16][68];
  __shared__ __align__(16) float Bs[16][68];
  int tid = threadIdx.x;
  int i0 = blockIdx.x * 64, j0 = blockIdx.y * 64;
  int tx = tid & 15, ty = tid >> 4;
  int aI = tid & 63, aK = (tid >> 6) << 2;
  int bJ = (tid & 15) << 2, bK = tid >> 4;
  float acc[4][4] = {};
  for (int k0 = 0; k0 < D; k0 += 16) {
    float4 av = *(const float4*)(A + (size_t)(i0 + aI) * D + k0 + aK);
    float4 bv = *(const float4*)(B + (size_t)(k0 + bK) * H + j0 + bJ);
    __syncthreads();
    As[aK + 0][aI] = av.x; As[aK + 1][aI] = av.y; As[aK + 2][aI] = av.z; As[aK + 3][aI] = av.w;
    *(float4*)(&Bs[bK][bJ]) = bv;
    __syncthreads();
#pragma unroll
    for (int kk = 0; kk < 16; kk++) {
      float4 a4 = *(float4*)(&As[kk][ty << 2]);
      float4 b4 = *(float4*)(&Bs[kk][tx << 2]);
      float aa[4] = {a4.x, a4.y, a4.z, a4.w};
      float bb[4] = {b4.x, b4.y, b4.z, b4.w};
#pragma unroll
      for (int p = 0; p < 4; p++)
#pragma unroll
        for (int q = 0; q < 4; q++)
          acc[p][q] = fmaf(aa[p], bb[q], acc[p][q]);
    }
  }
#pragma unroll
  for (int p = 0; p < 4; p++) {
    int i = i0 + (ty << 2) + p;
    float o[4];
#pragma unroll
    for (int q = 0; q < 4; q++) {
      int j = j0 + (tx << 2) + q;
      o[q] = selu_f(acc[p][q] + bias[j]);
    }
    *(float4*)(C + (size_t)i * H + j0 + (tx << 2)) = make_float4(o[0], o[1], o[2], o[3]);
  }
}

// Ms[r][j] = -max(0, |h_r|^2+|p_j|^2-2*dot)/tau*log2e, rows type-sorted.
__global__ __launch_bounds__(256) void k_msort(const float* __restrict__ h,
    const float* __restrict__ P, const int* __restrict__ perm,
    float* __restrict__ Ms, int n, int H, int k) {
  __shared__ __align__(16) float As[16][68];
  __shared__ __align__(16) float Bs[16][68];
  __shared__ float hp[4][64];
  __shared__ float pp[4][64];
  __shared__ int gIdx[64];
  int tid = threadIdx.x;
  int i0 = blockIdx.x * 64, j0 = blockIdx.y * 64;
  if (tid < 64) gIdx[tid] = perm[i0 + tid];
  __syncthreads();
  int tx = tid & 15, ty = tid >> 4;
  int aI = tid & 63, aK = (tid >> 6) << 2;
  int gA = gIdx[aI];
  bool bok = (j0 + aI) < k;
  const float* bRow = P + (size_t)(j0 + (bok ? aI : 0)) * H;
  float acc[4][4] = {};
  float ha = 0.f, pa = 0.f;
  for (int k0 = 0; k0 < H; k0 += 16) {
    float4 av = *(const float4*)(h + (size_t)gA * H + k0 + aK);
    float4 bv = *(const float4*)(bRow + k0 + aK);
    ha += av.x * av.x + av.y * av.y + av.z * av.z + av.w * av.w;
    pa += bv.x * bv.x + bv.y * bv.y + bv.z * bv.z + bv.w * bv.w;
    __syncthreads();
    As[aK + 0][aI] = av.x; As[aK + 1][aI] = av.y; As[aK + 2][aI] = av.z; As[aK + 3][aI] = av.w;
    Bs[aK + 0][aI] = bv.x; Bs[aK + 1][aI] = bv.y; Bs[aK + 2][aI] = bv.z; Bs[aK + 3][aI] = bv.w;
    __syncthreads();
#pragma unroll
    for (int kk = 0; kk < 16; kk++) {
      float4 a4 = *(float4*)(&As[kk][ty << 2]);
      float4 b4 = *(float4*)(&Bs[kk][tx << 2]);
      float aa[4] = {a4.x, a4.y, a4.z, a4.w};
      float bb[4] = {b4.x, b4.y, b4.z, b4.w};
#pragma unroll
      for (int p = 0; p < 4; p++)
#pragma unroll
        for (int q = 0; q < 4; q++)
          acc[p][q] = fmaf(aa[p], bb[q], acc[p][q]);
    }
  }
  int grp = tid >> 6;
  hp[grp][aI] = ha;
  pp[grp][aI] = pa;
  __syncthreads();
#pragma unroll
  for (int p = 0; p < 4; p++) {
    int rr = (ty << 2) + p;
    int r = i0 + rr;
    float hq = hp[0][rr] + hp[1][rr] + hp[2][rr] + hp[3][rr];
#pragma unroll
    for (int q = 0; q < 4; q++) {
      int jl = (tx << 2) + q;
      int j = j0 + jl;
      if (j < k) {
        float pq = pp[0][jl] + pp[1][jl] + pp[2][jl] + pp[3][jl];
        float d2 = hq + pq - 2.f * acc[p][q];
        d2 = fmaxf(d2, 0.f);
        Ms[(size_t)r * k + j] = -d2 * MSCALE2;
      }
    }
  }
}

// Persistent Sinkhorn, LINEAR domain, TWO blocks per type (34 blocks), K' bf16
// resident in LDS with 656-B padded row stride (no quad bank alias; spill rows
// read from global Ms2). Row pass: 16-lane-group layout, register-chunked
// {rs pass -> w gate -> u/acc pass} so the lagged cross-block Sigma-u latency
// is covered by the rs compute. Column sums: pairwise partner exchange.
// Colmax: one-time pairwise prologue exchange. (= R3 structure + LDS pad.)
__global__ __launch_bounds__(1024) void k_sink(const float* __restrict__ Ms,
    unsigned short* __restrict__ Ms2, const int* __restrict__ meta,
    float* __restrict__ cmD, unsigned* __restrict__ cmE,
    float* __restrict__ pcD, unsigned* __restrict__ pcE,
    float* __restrict__ suD, unsigned* __restrict__ suE,
    float* __restrict__ uF, float* __restrict__ vF,
    int k, float tm_last) {
  __shared__ __align__(16) char Klds[LCAP * LROW];          // 131,200 B
  __shared__ __align__(16) float WP2[16][KP];               //  20,480 B
  __shared__ __align__(16) float V[KP];                     //   1,280 B
  __shared__ __align__(16) float Sown[KP];                  //   1,280 B
  __shared__ float SU[16];
  __shared__ float w_sh;
  __shared__ int lvl_ep;
  __shared__ int pairflag;
  int tid = threadIdx.x, lane = tid & 63, wv = tid >> 6;
  int c = blockIdx.x;            // 0..33
  int t = c >> 1, hb = c & 1, prt = c ^ 1;
  int cRt = meta[t];
  int s0t = meta[32 + t];
  int h0 = (cRt + 1) >> 1;
  int rb = hb ? h0 : 0;
  int re = hb ? cRt : h0;
  int myR = re - rb;
  int s0 = s0t + rb;
  int ntH = (myR + 3) >> 2;      // tiles of 4 rows (own half)
  bool l2v = (lane + 64) < (k >> 2);   // fp32-prologue second-half lanes
  int g = lane >> 4, cg = lane & 15;   // row-in-quad, col-group
  bool r2a = (cg < 8);                 // cols 256..319 active lanes

  if (tid == 0) { w_sh = 1.f; lvl_ep = 0; pairflag = 0; }

  // ---- prologue pass 1: own-half colmax -> pair exchange -> full colmax ----
  {
    float4 cm0 = make_float4(-3e38f, -3e38f, -3e38f, -3e38f);
    float4 cm1 = cm0;
    for (int tile = wv; tile < ntH; tile += 16) {
      int r0 = tile * 4;
#pragma unroll
      for (int rr = 0; rr < 4; rr++) {
        int rc = (r0 + rr < myR) ? (r0 + rr) : r0;
        const float4* rp = (const float4*)(Ms + (size_t)(s0 + rc) * k);
        float4 a0 = rp[lane];
        cm0.x = fmaxf(cm0.x, a0.x); cm0.y = fmaxf(cm0.y, a0.y);
        cm0.z = fmaxf(cm0.z, a0.z); cm0.w = fmaxf(cm0.w, a0.w);
        if (l2v) {
          float4 a1 = rp[lane + 64];
          cm1.x = fmaxf(cm1.x, a1.x); cm1.y = fmaxf(cm1.y, a1.y);
          cm1.z = fmaxf(cm1.z, a1.z); cm1.w = fmaxf(cm1.w, a1.w);
        }
      }
    }
    *(float4*)&WP2[wv][4 * lane] = cm0;
    if (l2v) *(float4*)&WP2[wv][4 * (lane + 64)] = cm1;
    __syncthreads();
    if (tid < k) {
      float cmax = WP2[0][tid];
#pragma unroll
      for (int q = 1; q < 16; q++) cmax = fmaxf(cmax, WP2[q][tid]);
      Sown[tid] = cmax;
      __hip_atomic_store(&cmD[c * KP + tid], cmax,
                         __ATOMIC_RELAXED, __HIP_MEMORY_SCOPE_AGENT);
    }
    __syncthreads();  // drains all cmD stores
    if (tid == 0) {
      __hip_atomic_store(&cmE[c * 16], 1u, __ATOMIC_RELAXED, __HIP_MEMORY_SCOPE_AGENT);
      while (__hip_atomic_load(&cmE[prt * 16], __ATOMIC_RELAXED, __HIP_MEMORY_SCOPE_AGENT) < 1u)
        __builtin_amdgcn_s_sleep(1);
      __hip_atomic_store(&pairflag, 1, __ATOMIC_RELEASE, __HIP_MEMORY_SCOPE_WORKGROUP);
    }
    if (tid < k) {
      while (__hip_atomic_load(&pairflag, __ATOMIC_ACQUIRE, __HIP_MEMORY_SCOPE_WORKGROUP) < 1)
        __builtin_amdgcn_s_sleep(1);
      float o = __hip_atomic_load(&cmD[prt * KP + tid],
                                  __ATOMIC_RELAXED, __HIP_MEMORY_SCOPE_AGENT);
      V[tid] = fmaxf(Sown[tid], o);
    }
    __syncthreads();
    // ---- pass 2: K' = 2^(M - cmax) -> bf16, to global Ms2 + LDS rows ----
    float4 cx0 = *(const float4*)&V[4 * lane];
    float4 cx1 = l2v ? *(const float4*)&V[4 * (lane + 64)] : cx0;
    for (int tile = wv; tile < ntH; tile += 16) {
      int r0 = tile * 4;
#pragma unroll
      for (int rr = 0; rr < 4; rr++) {
        int r = r0 + rr;
        if (r < myR) {
          const float4* rp = (const float4*)(Ms + (size_t)(s0 + r) * k);
          char* orow = (char*)Ms2 + (size_t)(s0 + r) * (KP * 2);
          char* lrow = Klds + (size_t)r * LROW;
          bool inL = (r < LCAP);
          float4 a0 = rp[lane];
          uint2 o;
          o.x = bfp(EX2(a0.x - cx0.x), EX2(a0.y - cx0.y));
          o.y = bfp(EX2(a0.z - cx0.z), EX2(a0.w - cx0.w));
          *(uint2*)(orow + 8 * lane) = o;
          if (inL) *(uint2*)(lrow + 8 * lane) = o;
          if (l2v) {
            float4 a1 = rp[lane + 64];
            uint2 o1;
            o1.x = bfp(EX2(a1.x - cx1.x), EX2(a1.y - cx1.y));
            o1.y = bfp(EX2(a1.z - cx1.z), EX2(a1.w - cx1.w));
            *(uint2*)(orow + 512 + 8 * lane) = o1;
            if (inL) *(uint2*)(lrow + 512 + 8 * lane) = o1;
          } else if (lane < 16) {
            *(uint2*)(orow + 512 + 8 * lane) = make_uint2(0u, 0u);  // pad cols
            if (inL) *(uint2*)(lrow + 512 + 8 * lane) = make_uint2(0u, 0u);
          }
        }
      }
    }
  }
  __syncthreads();
  if (tid < KP) V[tid] = 0.f;  // v~ init (underflow-equivalent to reference)
  __syncthreads();

  for (int m = 0; m < NITER; m++) {
    int epoch = m + 1;
    int slot = m & 3;
    // ---- wave 15 (exchange-only): consume Sigma-u_{m-1} over 34 blocks ----
    if (wv == 15) {
      if (m > 0) {
        int pslot = (m - 1) & 3;
        unsigned want = (unsigned)m;
        bool need = lane < NBLK;
        for (;;) {
          bool ok = !need ||
              (__hip_atomic_load(&suE[(pslot * NBLK + lane) * 16],
                                 __ATOMIC_RELAXED, __HIP_MEMORY_SCOPE_AGENT) >= want);
          if (__all(ok)) break;
          __builtin_amdgcn_s_sleep(1);
        }
        float s = need
            ? __hip_atomic_load(&suD[(pslot * NBLK + lane) * 16],
                                __ATOMIC_RELAXED, __HIP_MEMORY_SCOPE_AGENT)
            : 0.f;
#pragma unroll
        for (int o = 32; o; o >>= 1) s += __shfl_xor(s, o);
        if (lane == 0) w_sh = tm_last / s;
      }
      if (lane == 0)
        __hip_atomic_store(&lvl_ep, epoch, __ATOMIC_RELEASE, __HIP_MEMORY_SCOPE_WORKGROUP);
    }
    // ---- phase A: LDS/L2-fed 16-lane-group row pass, register-chunked ----
    float w = 0.f;
    bool haveW = (wv == 15);
    float su = 0.f;
    float vv[3][8];
#pragma unroll
    for (int q3 = 0; q3 < 3; q3++) {
      if (q3 < 2 || r2a) {
        float4 x0 = *(const float4*)&V[q3 * 128 + cg * 8];
        float4 x1 = *(const float4*)&V[q3 * 128 + cg * 8 + 4];
        vv[q3][0] = x0.x; vv[q3][1] = x0.y; vv[q3][2] = x0.z; vv[q3][3] = x0.w;
        vv[q3][4] = x1.x; vv[q3][5] = x1.y; vv[q3][6] = x1.z; vv[q3][7] = x1.w;
      } else {
#pragma unroll
        for (int e = 0; e < 8; e++) vv[q3][e] = 0.f;
      }
    }
    float acc[3][8];
#pragma unroll
    for (int q3 = 0; q3 < 3; q3++)
#pragma unroll
      for (int e = 0; e < 8; e++) acc[q3][e] = 0.f;

    int t0 = (wv < 15) ? wv : ntH;   // wave 15 does no row work
    for (; t0 < ntH; t0 += 15 * CH) {
      uint4 T[CH][3];
      float rs[CH];
      // -- rs pass: load tiles (kept in regs), dot with v~ --
#pragma unroll
      for (int ccc = 0; ccc < CH; ccc++) {
        int tile = t0 + 15 * ccc;
        rs[ccc] = 0.f;
        if (tile < ntH) {
          int r = tile * 4 + g;
          int rc = (r < myR) ? r : (myR - 1);
          uint4 z4 = make_uint4(0u, 0u, 0u, 0u);
          if (rc < LCAP) {
            const uint4* lp = (const uint4*)(Klds + (size_t)rc * LROW + (cg << 4));
            T[ccc][0] = lp[0];
            T[ccc][1] = lp[16];
            if (r2a) T[ccc][2] = lp[32]; else T[ccc][2] = z4;
          } else {
            const uint4* gp = (const uint4*)((const char*)Ms2 +
                (size_t)(s0 + rc) * (KP * 2) + (cg << 4));
            T[ccc][0] = gp[0];
            T[ccc][1] = gp[16];
            if (r2a) T[ccc][2] = gp[32]; else T[ccc][2] = z4;
          }
          float r1 = 0.f;
#pragma unroll
          for (int q3 = 0; q3 < 3; q3++) {
            r1 = fmaf(BFLO(T[ccc][q3].x), vv[q3][0], r1);
            r1 = fmaf(BFHI(T[ccc][q3].x), vv[q3][1], r1);
            r1 = fmaf(BFLO(T[ccc][q3].y), vv[q3][2], r1);
            r1 = fmaf(BFHI(T[ccc][q3].y), vv[q3][3], r1);
            r1 = fmaf(BFLO(T[ccc][q3].z), vv[q3][4], r1);
            r1 = fmaf(BFHI(T[ccc][q3].z), vv[q3][5], r1);
            r1 = fmaf(BFLO(T[ccc][q3].w), vv[q3][6], r1);
            r1 = fmaf(BFHI(T[ccc][q3].w), vv[q3][7], r1);
          }
          r1 += __shfl_xor(r1, 1); r1 += __shfl_xor(r1, 2);
          r1 += __shfl_xor(r1, 4); r1 += __shfl_xor(r1, 8);
          rs[ccc] = r1;
        }
      }
      // -- w gate (covered by the rs pass above; latches) --
      if (!haveW) {
        while (__hip_atomic_load(&lvl_ep, __ATOMIC_ACQUIRE, __HIP_MEMORY_SCOPE_WORKGROUP) < epoch)
          __builtin_amdgcn_s_sleep(1);
        w = w_sh;
        haveW = true;
      }
      // -- u / acc pass (tiles still in regs) --
#pragma unroll
      for (int ccc = 0; ccc < CH; ccc++) {
        int tile = t0 + 15 * ccc;
        if (tile < ntH) {
          int r = tile * 4 + g;
          bool valid = (r < myR);
          float u = RCP(rs[ccc] + w);
          float uu = valid ? u : 0.f;
          if (cg == 0) {
            su += uu;
            if (valid && m == NITER - 1) uF[s0 + r] = u;
          }
#pragma unroll
          for (int q3 = 0; q3 < 3; q3++) {
            acc[q3][0] = fmaf(BFLO(T[ccc][q3].x), uu, acc[q3][0]);
            acc[q3][1] = fmaf(BFHI(T[ccc][q3].x), uu, acc[q3][1]);
            acc[q3][2] = fmaf(BFLO(T[ccc][q3].y), uu, acc[q3][2]);
            acc[q3][3] = fmaf(BFHI(T[ccc][q3].y), uu, acc[q3][3]);
            acc[q3][4] = fmaf(BFLO(T[ccc][q3].z), uu, acc[q3][4]);
            acc[q3][5] = fmaf(BFHI(T[ccc][q3].z), uu, acc[q3][5]);
            acc[q3][6] = fmaf(BFLO(T[ccc][q3].w), uu, acc[q3][6]);
            acc[q3][7] = fmaf(BFHI(T[ccc][q3].w), uu, acc[q3][7]);
          }
        }
      }
    }
    if (!haveW) {  // zero-tile waves still ratchet the epoch
      while (__hip_atomic_load(&lvl_ep, __ATOMIC_ACQUIRE, __HIP_MEMORY_SCOPE_WORKGROUP) < epoch)
        __builtin_amdgcn_s_sleep(1);
      haveW = true;
    }

    if (wv < 15) {
      // reduce colsum partials across the 4 row-groups, lanes 0..15 store
#pragma unroll
      for (int q3 = 0; q3 < 3; q3++)
#pragma unroll
        for (int e = 0; e < 8; e++) {
          float a = acc[q3][e];
          a += __shfl_xor(a, 16);
          a += __shfl_xor(a, 32);
          acc[q3][e] = a;
        }
      if (lane < 16) {
#pragma unroll
        for (int q3 = 0; q3 < 3; q3++) {
          if (q3 < 2 || lane < 8) {
            *(float4*)&WP2[wv][q3 * 128 + lane * 8] =
                make_float4(acc[q3][0], acc[q3][1], acc[q3][2], acc[q3][3]);
            *(float4*)&WP2[wv][q3 * 128 + lane * 8 + 4] =
                make_float4(acc[q3][4], acc[q3][5], acc[q3][6], acc[q3][7]);
          }
        }
      }
      float sr = su;
      sr += __shfl_xor(sr, 16);
      sr += __shfl_xor(sr, 32);
      if (lane == 0) SU[wv] = sr;
    }
    __syncthreads();
    // ---- publish own col partial + block Sigma-u ----
    if (tid < k) {
      float s = WP2[0][tid];
#pragma unroll
      for (int q = 1; q < 15; q++) s += WP2[q][tid];
      Sown[tid] = s;
      __hip_atomic_store(&pcD[(slot * NBLK + c) * KP + tid], s,
                         __ATOMIC_RELAXED, __HIP_MEMORY_SCOPE_AGENT);
    }
    if (wv == 15) {
      float sp = (lane < 15) ? SU[lane] : 0.f;
#pragma unroll
      for (int o = 32; o; o >>= 1) sp += __shfl_xor(sp, o);
      if (lane == 0)
        __hip_atomic_store(&suD[(slot * NBLK + c) * 16], sp,
                           __ATOMIC_RELAXED, __HIP_MEMORY_SCOPE_AGENT);
      __builtin_amdgcn_s_waitcnt(0);
      if (lane == 0)
        __hip_atomic_store(&suE[(slot * NBLK + c) * 16], (unsigned)epoch,
                           __ATOMIC_RELAXED, __HIP_MEMORY_SCOPE_AGENT);
    }
    __syncthreads();  // drains all pcD stores
    // ---- pairwise combine: epoch handshake, partner read, V = rcp(sum) ----
    if (tid == 0) {
      __hip_atomic_store(&pcE[(slot * NBLK + c) * 16], (unsigned)epoch,
                         __ATOMIC_RELAXED, __HIP_MEMORY_SCOPE_AGENT);
      while (__hip_atomic_load(&pcE[(slot * NBLK + prt) * 16],
                               __ATOMIC_RELAXED, __HIP_MEMORY_SCOPE_AGENT) < (unsigned)epoch)
        __builtin_amdgcn_s_sleep(1);
      __hip_atomic_store(&pairflag, m + 2, __ATOMIC_RELEASE, __HIP_MEMORY_SCOPE_WORKGROUP);
    }
    if (tid < k) {
      while (__hip_atomic_load(&pairflag, __ATOMIC_ACQUIRE, __HIP_MEMORY_SCOPE_WORKGROUP) < m + 2)
        __builtin_amdgcn_s_sleep(1);
      float sp = __hip_atomic_load(&pcD[(slot * NBLK + prt) * KP + tid],
                                   __ATOMIC_RELAXED, __HIP_MEMORY_SCOPE_AGENT);
      V[tid] = RCP(Sown[tid] + sp);
    }
    __syncthreads();
  }
  if (hb == 0)
    for (int j = tid; j < k; j += 1024) vF[(size_t)t * k + j] = V[j];
}

// epilogue (linear): T_rj = K'_rj·u_r·v~_j; logits = ln(T+1e-8); T scatter with
// incremental mod-17 and NONTEMPORAL stores (write-only output). K' read bf16.
__global__ __launch_bounds__(256) void k_epi(const unsigned short* __restrict__ Ms2,
    const float* __restrict__ uF, const float* __restrict__ vF,
    const int* __restrict__ perm, const int* __restrict__ tys,
    float* __restrict__ out, int n, int k) {
  __shared__ float vals[KCAP];
  int r = blockIdx.x;
  int i = perm[r], t = tys[r];
  float u = uF[r];
  const unsigned short* Krow = Ms2 + (size_t)r * KP;
  const float* Vrow = vF + (size_t)t * k;
  for (int j = threadIdx.x; j < k; j += 256)
    vals[j] = __uint_as_float((unsigned)Krow[j] << 16) * u * Vrow[j];
  __syncthreads();
  float* lg = out + (size_t)i * k;
  for (int j = threadIdx.x; j < k; j += 256)
    __builtin_nontemporal_store(LG2(vals[j] + 1e-8f) * 0.6931471805599453f, &lg[j]);
  int ns = k * NT;
  float* Trow = out + (size_t)n * k + (size_t)i * ns;
  if ((ns & 3) == 0) {
    int n4 = ns >> 2;
    int o0 = threadIdx.x << 2;
    int rmod = o0 % NT;
    for (int g4 = threadIdx.x; g4 < n4; g4 += 256, o0 += 1024) {
      int sstar = t - rmod; if (sstar < 0) sstar += NT;
      int j = (unsigned)(o0 + sstar) / (unsigned)NT;
      float vv = vals[j < k ? j : 0];
      vfloat4 v;
      v.x = (sstar == 0) ? vv : 0.f;
      v.y = (sstar == 1) ? vv : 0.f;
      v.z = (sstar == 2) ? vv : 0.f;
      v.w = (sstar == 3) ? vv : 0.f;
      __builtin_nontemporal_store(v, (vfloat4*)(Trow + o0));
      rmod += 4; if (rmod >= NT) rmod -= NT;
    }
  } else {
    for (int o = threadIdx.x; o < ns; o += 256) {
      int j = o / NT;
      int tt = o - j * NT;
      Trow[o] = (tt == t) ? vals[j] : 0.f;
    }
  }
}

extern "C" void kernel_launch(void* const* d_in, const int* in_sizes, int n_in,
                              void* d_out, int out_size, void* d_ws, size_t ws_size,
                              hipStream_t stream) {
  const float* emb = (const float*)d_in[0];
  const float* W1  = (const float*)d_in[1];
  const float* b1  = (const float*)d_in[2];
  const float* P   = (const float*)d_in[3];
  const int*   jt  = (const int*)d_in[4];
  (void)n_in; (void)ws_size;

  const int n = in_sizes[4];
  const int H = in_sizes[2];
  const int D = in_sizes[1] / H;
  const int k = out_size / (n * (NT + 1));
  const int nslots = k * NT;
  const float tm_last = (float)((n - nslots) > 1 ? (n - nslots) : 1);

  char* w = (char*)d_ws;
  size_t off = 0;
  auto take = [&](size_t bytes) -> char* {
    char* p = w + off;
    off = (off + bytes + 255) & ~(size_t)255;
    return p;
  };
  int*      meta = (int*)take(4096);
  int*      perm = (int*)take((size_t)n * 4);
  int*      tys  = (int*)take((size_t)n * 4);
  float*    h    = (float*)take((size_t)n * H * 4);
  float*    Ms   = (float*)take((size_t)n * k * 4);
  unsigned short* Ms2 = (unsigned short*)take((size_t)n * KP * 2 + 1024);
  float*    cmD  = (float*)take((size_t)NBLK * KP * 4);
  unsigned* cmE  = (unsigned*)take((size_t)NBLK * 64);
  float*    pcD  = (float*)take((size_t)4 * NBLK * KP * 4);
  unsigned* pcE  = (unsigned*)take((size_t)4 * NBLK * 64);
  float*    suD  = (float*)take((size_t)4 * NBLK * 64);
  unsigned* suE  = (unsigned*)take((size_t)4 * NBLK * 64);
  float*    uF   = (float*)take((size_t)n * 4);
  float*    vF   = (float*)take((size_t)NT * k * 4);

  (void)hipMemsetAsync(cmE, 0, (size_t)NBLK * 64, stream);
  (void)hipMemsetAsync(pcE, 0, (size_t)4 * NBLK * 64, stream);
  (void)hipMemsetAsync(suE, 0, (size_t)4 * NBLK * 64, stream);
  k_bucket<<<1, 1024, 0, stream>>>(jt, n, meta, perm, tys);
  k_hgemm<<<dim3(n / 64, H / 64), dim3(256), 0, stream>>>(emb, W1, b1, h, n, D, H);
  k_msort<<<dim3(n / 64, (k + 63) / 64), dim3(256), 0, stream>>>(h, P, perm, Ms, n, H, k);
  k_sink<<<NBLK, 1024, 0, stream>>>(Ms, Ms2, meta, cmD, cmE, pcD, pcE,
                                    suD, suE, uF, vF, k, tm_last);
  k_epi<<<n, 256, 0, stream>>>(Ms2, uF, vF, perm, tys, (float*)d_out, n, k);
}